// Round 2
// baseline (363.852 us; speedup 1.0000x reference)
//
#include <hip/hip_runtime.h>
#include <hip/hip_bf16.h>

#define BB 4
#define CC 256
#define NN 4096

typedef __attribute__((ext_vector_type(8))) short short8;
typedef __attribute__((ext_vector_type(4))) float floatx4;
typedef __attribute__((ext_vector_type(4))) unsigned short ushortx4;

__device__ __forceinline__ float bf2f(unsigned short u) {
  union { unsigned int i; float f; } cv; cv.i = ((unsigned int)u) << 16; return cv.f;
}
__device__ __forceinline__ unsigned short f2bf(float f) {
  union { __hip_bfloat16 h; unsigned short u; } cv; cv.h = __float2bfloat16(f); return cv.u;
}

#define MFMA(a, b, c) __builtin_amdgcn_mfma_f32_16x16x32_bf16((a), (b), (c), 0, 0, 0)

// ---------------------------------------------------------------------------
// Phase 0: convert fp32 weights -> bf16 (once; tiny).
// ---------------------------------------------------------------------------
__global__ __launch_bounds__(256) void wcvt(const float* __restrict__ w0,
                                            const float* __restrict__ w1,
                                            const float* __restrict__ w2,
                                            unsigned short* __restrict__ o0,
                                            unsigned short* __restrict__ o1,
                                            unsigned short* __restrict__ o2) {
  const float* w = (blockIdx.y == 0) ? w0 : (blockIdx.y == 1) ? w1 : w2;
  unsigned short* o = (blockIdx.y == 0) ? o0 : (blockIdx.y == 1) ? o1 : o2;
  int i = (blockIdx.x * 256 + threadIdx.x) * 4;
  floatx4 v = *(const floatx4*)&w[i];
  ushortx4 p;
#pragma unroll
  for (int r = 0; r < 4; r++) p[r] = f2bf(v[r]);
  *(ushortx4*)&o[i] = p;
}

// ---------------------------------------------------------------------------
// Phase 1: Xbf[b][n][c] = bf16( x[b][c][n] + PE(c, n) ), transposed via LDS.
// x is fp32 (B,C,N); Xbf is bf16 (B,N,C).
// ---------------------------------------------------------------------------
__global__ __launch_bounds__(256) void prep_x(const float* __restrict__ x,
                                              unsigned short* __restrict__ Xbf) {
  __shared__ float tile[32][33];
  int b = blockIdx.z;
  int n0 = blockIdx.x * 32, c0 = blockIdx.y * 32;
  int tx = threadIdx.x, ty = threadIdx.y;
#pragma unroll
  for (int i = 0; i < 4; i++) {
    int c = c0 + ty + i * 8;
    int n = n0 + tx;
    float v = x[((long)(b * CC + c)) * NN + n];
    int hh = n >> 6, ww = n & 63;
    int j = c & 63;
    // inv[j] = 10000^(-j/64) = exp2(-j * log2(10000)/64)
    float freq = exp2f(-0.2076205059304601f * (float)j);
    float arg = (float)((c < 128) ? ww : hh) * freq;
    v += (c & 64) ? cosf(arg) : sinf(arg);
    tile[ty + i * 8][tx] = v;
  }
  __syncthreads();
#pragma unroll
  for (int i = 0; i < 4; i++) {
    int n = n0 + ty + i * 8;
    int c = c0 + tx;
    Xbf[((long)(b * NN + n)) * CC + c] = f2bf(tile[tx][ty + i * 8]);
  }
}

// ---------------------------------------------------------------------------
// Phase 2: generic C = A * Bt^T, all bf16, K=256 fixed.
//   A: (M x 256) row-major, Bt: (Nc_rows x 256) row-major, Out: (M x Nc) bf16.
// 64x64 tile per WG, 4 waves, wave owns 16 output rows (m92 convention).
// ---------------------------------------------------------------------------
__global__ __launch_bounds__(256, 2) void gemm_bt(const unsigned short* __restrict__ A, long asb,
                                                  const unsigned short* __restrict__ Bt, long bsb,
                                                  unsigned short* __restrict__ O, long osb,
                                                  int Nc) {
  __shared__ alignas(16) unsigned short Al[64][40];  // stride 80B: <=2-way banks (free)
  __shared__ alignas(16) unsigned short Bl[64][40];
  int b = blockIdx.z;
  const unsigned short* Ab = A + (long)b * asb;
  const unsigned short* Bb = Bt + (long)b * bsb;
  unsigned short* Ob = O + (long)b * osb;
  long row0 = (long)blockIdx.y * 64, col0 = (long)blockIdx.x * 64;
  int t = threadIdx.x, wave = t >> 6, lane = t & 63, quad = lane >> 4, l15 = lane & 15;
  int sr = t >> 2, sk = (t & 3) * 8;
  floatx4 acc[4] = {};
#pragma unroll
  for (int k0 = 0; k0 < 256; k0 += 32) {
    short8 av = *(const short8*)&Ab[(row0 + sr) * 256 + k0 + sk];
    short8 bv = *(const short8*)&Bb[(col0 + sr) * 256 + k0 + sk];
    __syncthreads();
    *(short8*)&Al[sr][sk] = av;
    *(short8*)&Bl[sr][sk] = bv;
    __syncthreads();
    short8 af = *(const short8*)&Al[wave * 16 + l15][quad * 8];
#pragma unroll
    for (int cb = 0; cb < 4; cb++) {
      short8 bf = *(const short8*)&Bl[cb * 16 + l15][quad * 8];
      acc[cb] = MFMA(af, bf, acc[cb]);
    }
  }
  // C/D layout (m89): col = lane&15, row = quad*4 + reg
#pragma unroll
  for (int cb = 0; cb < 4; cb++) {
#pragma unroll
    for (int r = 0; r < 4; r++) {
      long row = row0 + wave * 16 + quad * 4 + r;
      long col = col0 + cb * 16 + l15;
      Ob[row * (long)Nc + col] = f2bf(acc[cb][r]);
    }
  }
}

// ---------------------------------------------------------------------------
// Phase 3: flash attention. One WG = 64 Q-rows of one batch; 4 waves, each
// wave owns 16 Q-rows. K-tile = 32 keys. Q fragments in registers.
// Q,K: (B,N,C) bf16; Vt: (B,C,N) bf16. Out: (B,C,N) fp32.
// ---------------------------------------------------------------------------
__global__ __launch_bounds__(256, 1) void attn(const unsigned short* __restrict__ Qg,
                                               const unsigned short* __restrict__ Kg,
                                               const unsigned short* __restrict__ Vtg,
                                               float* __restrict__ Out) {
  __shared__ alignas(16) unsigned short Kl[32][264];    // stride 528B -> 2-way (free)
  __shared__ alignas(16) unsigned short Vl[256][40];    // stride 80B  -> 2-way (free)
  __shared__ alignas(16) unsigned short Pl[4][16][40];  // per-wave P round-trip
  int b = blockIdx.y;
  long q0 = (long)blockIdx.x * 64;
  int t = threadIdx.x, wave = t >> 6, lane = t & 63, quad = lane >> 4, l15 = lane & 15;
  const unsigned short* Qb = Qg + (long)b * NN * CC;
  const unsigned short* Kb = Kg + (long)b * NN * CC;
  const unsigned short* Vb = Vtg + (long)b * CC * NN;

  // Q fragments: A-layout A[m=lane&15][k=quad*8+j], k = d in [0,256)
  short8 qf[8];
  long qrow = q0 + wave * 16 + l15;
#pragma unroll
  for (int ks = 0; ks < 8; ks++)
    qf[ks] = *(const short8*)&Qb[qrow * 256 + ks * 32 + quad * 8];

  floatx4 acc[16] = {};
  float mrow[4] = {-INFINITY, -INFINITY, -INFINITY, -INFINITY};
  float lrow[4] = {0.f, 0.f, 0.f, 0.f};

  int kr = t >> 3, kc = (t & 7) * 8;  // K staging
  int vr = t >> 2, vc = (t & 3) * 8;  // Vt staging

  const float sc = 0.0625f * 1.4426950408889634f;  // scale * log2(e)

  for (int m0 = 0; m0 < NN; m0 += 32) {
    __syncthreads();  // previous tile fully consumed
#pragma unroll
    for (int ch = 0; ch < 4; ch++)
      *(short8*)&Kl[kr][kc + ch * 64] = *(const short8*)&Kb[(long)(m0 + kr) * 256 + kc + ch * 64];
#pragma unroll
    for (int ch = 0; ch < 4; ch++) {
      int d = ch * 64 + vr;
      *(short8*)&Vl[d][vc] = *(const short8*)&Vb[(long)d * NN + m0 + vc];
    }
    __syncthreads();

    // S = Q K^T  (16 q-rows x 32 keys per wave)
    floatx4 s[2];
#pragma unroll
    for (int mt = 0; mt < 2; mt++) {
      floatx4 z = {0.f, 0.f, 0.f, 0.f};
      s[mt] = z;
#pragma unroll
      for (int ks = 0; ks < 8; ks++) {
        short8 kf = *(const short8*)&Kl[mt * 16 + l15][ks * 32 + quad * 8];
        s[mt] = MFMA(qf[ks], kf, s[mt]);
      }
    }

    // online softmax in exp2 domain; row r (= quad*4+reg) stats via width-16 shuffles
    float mn[4], al[4];
#pragma unroll
    for (int r = 0; r < 4; r++) {
      s[0][r] *= sc;
      s[1][r] *= sc;
      float v = fmaxf(s[0][r], s[1][r]);
      v = fmaxf(v, __shfl_xor(v, 1));
      v = fmaxf(v, __shfl_xor(v, 2));
      v = fmaxf(v, __shfl_xor(v, 4));
      v = fmaxf(v, __shfl_xor(v, 8));
      mn[r] = fmaxf(mrow[r], v);
      al[r] = exp2f(mrow[r] - mn[r]);
      mrow[r] = mn[r];
    }
#pragma unroll
    for (int r = 0; r < 4; r++) {
      unsigned short pb0 = f2bf(exp2f(s[0][r] - mn[r]));
      unsigned short pb1 = f2bf(exp2f(s[1][r] - mn[r]));
      float rs = bf2f(pb0) + bf2f(pb1);  // accumulate exactly what PV will use
      rs += __shfl_xor(rs, 1);
      rs += __shfl_xor(rs, 2);
      rs += __shfl_xor(rs, 4);
      rs += __shfl_xor(rs, 8);
      lrow[r] = lrow[r] * al[r] + rs;
      Pl[wave][quad * 4 + r][l15] = pb0;
      Pl[wave][quad * 4 + r][16 + l15] = pb1;
    }
#pragma unroll
    for (int db = 0; db < 16; db++) {
      acc[db][0] *= al[0];
      acc[db][1] *= al[1];
      acc[db][2] *= al[2];
      acc[db][3] *= al[3];
    }
    // Cross-lane LDS exchange within the wave: HW LDS pipe is in-order per
    // wave; the clobber stops the compiler reordering the read before writes.
    __asm__ volatile("" ::: "memory");
    short8 pf = *(const short8*)&Pl[wave][l15][quad * 8];
#pragma unroll
    for (int db = 0; db < 16; db++) {
      short8 vf = *(const short8*)&Vl[db * 16 + l15][quad * 8];
      acc[db] = MFMA(pf, vf, acc[db]);
    }
  }

  // epilogue: Out[b][d][n] = O[n][d] / l[n]; 4 consecutive n per lane (float4)
  float il[4];
#pragma unroll
  for (int r = 0; r < 4; r++) il[r] = 1.0f / lrow[r];
  long nidx = q0 + wave * 16 + quad * 4;
#pragma unroll
  for (int db = 0; db < 16; db++) {
    long d = db * 16 + l15;
    floatx4 o;
#pragma unroll
    for (int r = 0; r < 4; r++) o[r] = acc[db][r] * il[r];
    *(floatx4*)&Out[((long)b * CC + d) * NN + nidx] = o;
  }
}

// ---------------------------------------------------------------------------
extern "C" void kernel_launch(void* const* d_in, const int* in_sizes, int n_in,
                              void* d_out, int out_size, void* d_ws, size_t ws_size,
                              hipStream_t stream) {
  const float* x = (const float*)d_in[0];
  const float* wq = (const float*)d_in[1];
  const float* wk = (const float*)d_in[2];
  const float* wv = (const float*)d_in[3];
  float* out = (float*)d_out;

  char* ws = (char*)d_ws;
  unsigned short* Xbf = (unsigned short*)(ws);               // 8 MB (B,N,C)
  unsigned short* Qb = (unsigned short*)(ws + (8l << 20));   // 8 MB (B,N,C)
  unsigned short* Kb = (unsigned short*)(ws + (16l << 20));  // 8 MB (B,N,C)
  unsigned short* Vt = (unsigned short*)(ws + (24l << 20));  // 8 MB (B,C,N)
  unsigned short* Wq = (unsigned short*)(ws + (32l << 20));            // 128 KB
  unsigned short* Wk = (unsigned short*)(ws + (32l << 20) + (1 << 17)); // 128 KB
  unsigned short* Wv = (unsigned short*)(ws + (32l << 20) + (2 << 17)); // 128 KB

  wcvt<<<dim3(CC * CC / 1024, 3), 256, 0, stream>>>(wq, wk, wv, Wq, Wk, Wv);
  prep_x<<<dim3(NN / 32, CC / 32, BB), dim3(32, 8), 0, stream>>>(x, Xbf);
  // Q = X * Wq^T, K = X * Wk^T   (per batch: 4096x256)
  gemm_bt<<<dim3(CC / 64, NN / 64, BB), 256, 0, stream>>>(Xbf, (long)NN * CC, Wq, 0, Qb,
                                                          (long)NN * CC, CC);
  gemm_bt<<<dim3(CC / 64, NN / 64, BB), 256, 0, stream>>>(Xbf, (long)NN * CC, Wk, 0, Kb,
                                                          (long)NN * CC, CC);
  // Vt = Wv * X^T  (per batch: 256x4096), i.e. Vt[d][n] = V[n][d]
  gemm_bt<<<dim3(NN / 64, CC / 64, BB), 256, 0, stream>>>(Wv, 0, Xbf, (long)NN * CC, Vt,
                                                          (long)CC * NN, NN);
  attn<<<dim3(NN / 64, BB), 256, 0, stream>>>(Qb, Kb, Vt, out);
}